// Round 1
// baseline (328.068 us; speedup 1.0000x reference)
//
#include <hip/hip_runtime.h>

#define BB 16
#define TT 16
#define VV 512
#define FF 64
#define OO 64

using f32x4 = __attribute__((ext_vector_type(4))) float;
using s16x8 = __attribute__((ext_vector_type(8))) short;

__device__ __forceinline__ short f2bf(float f) {
    union { float f; unsigned int u; } v; v.f = f;
    unsigned int u = v.u;
    u += 0x7fffu + ((u >> 16) & 1u);
    return (short)(u >> 16);
}

// One block per (bt, vtile): 256 threads = 4 waves, each wave owns 16 rows of the
// 64-row output v-tile. LDS bf16 tiles are [row][64 k] with 16B-slot XOR swizzle.
__global__ __launch_bounds__(256, 2)
void cheb_kernel(const float* __restrict__ x, const float* __restrict__ Att,
                 const float* __restrict__ S, const float* __restrict__ Theta,
                 float* __restrict__ out)
{
    // LDS layout (total 51200 B):
    //  [0, 24576)   main:      cT1 | cT2 | xT      (bf16 64x64 swizzled tiles)
    //  [0, 32768)   epilogue:  Zl1 | Zl2 | Th1 | Th2
    //  [32768, ..)  xd f32 [64][65], deg partials, degv, Adiag, Sdiag
    __shared__ __align__(16) unsigned char smem[51200];
    short* cT1 = (short*)(smem);
    short* cT2 = (short*)(smem + 8192);
    short* xT  = (short*)(smem + 16384);
    short* Zl1 = (short*)(smem);
    short* Zl2 = (short*)(smem + 8192);
    short* Th1 = (short*)(smem + 16384);
    short* Th2 = (short*)(smem + 24576);
    float (*xd)[65] = (float (*)[65])(smem + 32768);   // 16640 B
    float* degpart  = (float*)(smem + 49408);          // 1024 B
    float* degv     = (float*)(smem + 50432);          // 256 B
    float* Adg      = (float*)(smem + 50688);          // 256 B
    float* Sdg      = (float*)(smem + 50944);          // 256 B

    const int tid  = threadIdx.x;
    const int lane = tid & 63;
    const int q    = tid >> 6;      // wave id (blockDim=256)
    const int wv   = q;

    // XCD-friendly decode: the 8 v-tiles of one (b,t) share wg%8 and sit within a
    // 64-wg window -> same XCD, temporally close (S row/col tiles meet in L2).
    const int wg = blockIdx.x;
    const int bt = (wg & 7) + ((wg >> 6) << 3);   // 0..255
    const int vt = (wg >> 3) & 7;                 // 0..7
    const int v0 = vt * 64;
    const int b  = bt >> 4;                       // bt = b*T + t

    const float* Sbt = S   + (size_t)bt * VV * VV;
    const float* Abt = Att + (size_t)b  * VV * VV;
    const float* xbt = x   + (size_t)bt * VV * FF;

    f32x4 zero = {0.0f, 0.0f, 0.0f, 0.0f};
    f32x4 acc1[4], acc2[4];
    #pragma unroll
    for (int i = 0; i < 4; ++i) { acc1[i] = zero; acc2[i] = zero; }
    float degacc = 0.0f;

    const int nbase = lane & 15;
    const int g     = lane >> 4;
    const int mrow  = wv * 16 + nbase;   // A-fragment row (tile-local v)
    const int moff  = mrow * 64;
    const int m7    = mrow & 7;

    // ---------------- main loop over u-tiles (K = 512) ----------------
    for (int ut = 0; ut < 8; ++ut) {
        const int u0 = ut * 64;
        #pragma unroll
        for (int si = 0; si < 2; ++si) {
            const int s  = q + si * 4;           // 16B k-slot (8 bf16)
            const int ub = u0 + s * 8;
            // S row segment (transposed access, per-thread contiguous 32 B)
            const float* srp = Sbt + (size_t)(v0 + lane) * VV + ub;
            float4 r0 = *(const float4*)(srp);
            float4 r1 = *(const float4*)(srp + 4);
            float srow[8] = {r0.x, r0.y, r0.z, r0.w, r1.x, r1.y, r1.z, r1.w};
            s16x8 p1, p2, px;
            #pragma unroll
            for (int e = 0; e < 8; ++e) {
                const int u = ub + e;
                float sc = Sbt[(size_t)u * VV + v0 + lane];  // S[u, v]  (coalesced)
                float av = Abt[(size_t)u * VV + v0 + lane];  // Att[b,u,v]
                float xv = xbt[(size_t)u * FF + lane];       // x[u, f=lane]
                float sm = fminf(sc, srow[e]);               // Smin[u,v]
                degacc += sm;
                float c1 = -av * sm;
                float c2 = 2.0f * av * sm * sm;
                if (u == v0 + lane) {                        // diagonal element
                    c1 = 0.0f; c2 = 0.0f;
                    Adg[lane] = av; Sdg[lane] = sm;
                }
                p1[e] = f2bf(c1);
                p2[e] = f2bf(c2);
                px[e] = f2bf(xv);
            }
            const int soff = lane * 64 + ((s ^ (lane & 7)) * 8);
            *(s16x8*)&cT1[soff] = p1;
            *(s16x8*)&cT2[soff] = p2;
            *(s16x8*)&xT [soff] = px;
        }
        __syncthreads();
        // Z[v,f] += sum_u c[u,v] * x[u,f]   (A = c^T, B = x, K = u)
        #pragma unroll
        for (int kk = 0; kk < 2; ++kk) {
            const int slotA = kk * 4 + g;
            s16x8 a1 = *(const s16x8*)&cT1[moff + ((slotA ^ m7) * 8)];
            s16x8 a2 = *(const s16x8*)&cT2[moff + ((slotA ^ m7) * 8)];
            #pragma unroll
            for (int nt = 0; nt < 4; ++nt) {
                const int nrow = nt * 16 + nbase;
                s16x8 bfr = *(const s16x8*)&xT[nrow * 64 + ((slotA ^ (nrow & 7)) * 8)];
                acc1[nt] = __builtin_amdgcn_mfma_f32_16x16x32_bf16(a1, bfr, acc1[nt], 0, 0, 0);
                acc2[nt] = __builtin_amdgcn_mfma_f32_16x16x32_bf16(a2, bfr, acc2[nt], 0, 0, 0);
            }
        }
        __syncthreads();
    }

    // ---------------- epilogue staging ----------------
    // Z tiles -> bf16 LDS (C layout: row=(lane>>4)*4+reg, col=lane&15)
    #pragma unroll
    for (int nt = 0; nt < 4; ++nt) {
        #pragma unroll
        for (int r = 0; r < 4; ++r) {
            const int vv = wv * 16 + g * 4 + r;
            const int ff = nt * 16 + nbase;
            const int ad = vv * 64 + (((ff >> 3) ^ (vv & 7)) * 8) + (ff & 7);
            Zl1[ad] = f2bf(acc1[nt][r]);
            Zl2[ad] = f2bf(acc2[nt][r]);
        }
    }
    const float* Tg0 = Theta;
    const float* Tg1 = Theta + FF * OO;
    const float* Tg2 = Theta + 2 * FF * OO;
    #pragma unroll
    for (int si = 0; si < 2; ++si) {
        const int s = q + si * 4;
        s16x8 t1, t2;
        #pragma unroll
        for (int e = 0; e < 8; ++e) {
            const int f = s * 8 + e;
            t1[e] = f2bf(Tg1[f * OO + lane]);
            t2[e] = f2bf(Tg2[f * OO + lane]);
        }
        const int soff = lane * 64 + ((s ^ (lane & 7)) * 8);
        *(s16x8*)&Th1[soff] = t1;
        *(s16x8*)&Th2[soff] = t2;
    }
    #pragma unroll
    for (int i = 0; i < 16; ++i) {
        const int vv = q * 16 + i;
        xd[vv][lane] = xbt[(size_t)(v0 + vv) * FF + lane];  // f32 x rows for diag
    }
    degpart[q * 64 + lane] = degacc;
    __syncthreads();
    if (tid < 64)
        degv[tid] = degpart[tid] + degpart[64 + tid] + degpart[128 + tid] + degpart[192 + tid];
    __syncthreads();

    // ---------------- off-diag epilogue GEMM: out = Z1@Th1 + Z2@Th2 ----------------
    f32x4 oacc[4];
    #pragma unroll
    for (int i = 0; i < 4; ++i) oacc[i] = zero;
    #pragma unroll
    for (int kk = 0; kk < 2; ++kk) {
        const int slotA = kk * 4 + g;
        s16x8 za1 = *(const s16x8*)&Zl1[moff + ((slotA ^ m7) * 8)];
        s16x8 za2 = *(const s16x8*)&Zl2[moff + ((slotA ^ m7) * 8)];
        #pragma unroll
        for (int nt = 0; nt < 4; ++nt) {
            const int nrow = nt * 16 + nbase;
            const int nad = nrow * 64 + ((slotA ^ (nrow & 7)) * 8);
            s16x8 b1 = *(const s16x8*)&Th1[nad];
            s16x8 b2 = *(const s16x8*)&Th2[nad];
            oacc[nt] = __builtin_amdgcn_mfma_f32_16x16x32_bf16(za1, b1, oacc[nt], 0, 0, 0);
            oacc[nt] = __builtin_amdgcn_mfma_f32_16x16x32_bf16(za2, b2, oacc[nt], 0, 0, 0);
        }
    }

    // ---------------- exact f32 diagonal path ----------------
    // G_k[v,o] = sum_f x[v,f] * Theta_k[f,o], accumulated in the C-layout mapping
    float G0a[4][4] = {{0}}, G1a[4][4] = {{0}}, G2a[4][4] = {{0}};
    for (int f = 0; f < 64; ++f) {
        float xf[4];
        #pragma unroll
        for (int r = 0; r < 4; ++r) xf[r] = xd[wv * 16 + g * 4 + r][f];
        #pragma unroll
        for (int nt = 0; nt < 4; ++nt) {
            const int oo = nt * 16 + nbase;
            float th0 = Tg0[f * OO + oo];
            float th1 = Tg1[f * OO + oo];
            float th2 = Tg2[f * OO + oo];
            #pragma unroll
            for (int r = 0; r < 4; ++r) {
                G0a[nt][r] = fmaf(xf[r], th0, G0a[nt][r]);
                G1a[nt][r] = fmaf(xf[r], th1, G1a[nt][r]);
                G2a[nt][r] = fmaf(xf[r], th2, G2a[nt][r]);
            }
        }
    }

    float* obt = out + (size_t)bt * VV * OO;
    #pragma unroll
    for (int r = 0; r < 4; ++r) {
        const int vloc = wv * 16 + g * 4 + r;
        const float Ad = Adg[vloc];
        const float Ld = degv[vloc] - Sdg[vloc] - 1.0f;
        const float w1 = Ad * Ld;
        const float w2 = Ad * (2.0f * Ld * Ld - 1.0f);
        #pragma unroll
        for (int nt = 0; nt < 4; ++nt) {
            const int oo = nt * 16 + nbase;
            float val = oacc[nt][r] + Ad * G0a[nt][r] + w1 * G1a[nt][r] + w2 * G2a[nt][r];
            val = fmaxf(val, 0.0f);
            obt[(size_t)(v0 + vloc) * OO + oo] = val;
        }
    }
}

extern "C" void kernel_launch(void* const* d_in, const int* in_sizes, int n_in,
                              void* d_out, int out_size, void* d_ws, size_t ws_size,
                              hipStream_t stream) {
    (void)in_sizes; (void)n_in; (void)d_ws; (void)ws_size; (void)out_size;
    const float* x   = (const float*)d_in[0];
    const float* Att = (const float*)d_in[1];
    const float* S   = (const float*)d_in[2];
    const float* Th  = (const float*)d_in[3];
    float* outp = (float*)d_out;
    hipLaunchKernelGGL(cheb_kernel, dim3(2048), dim3(256), 0, stream,
                       x, Att, S, Th, outp);
}

// Round 2
// 234.993 us; speedup vs baseline: 1.3961x; 1.3961x over previous
//
#include <hip/hip_runtime.h>

#define VV 512
#define FF 64
#define OO 64
#define YELEMS 8388608  // 256*512*64 elements per y tensor

using f32x4 = __attribute__((ext_vector_type(4))) float;
using s16x8 = __attribute__((ext_vector_type(8))) short;
using u16x4 = __attribute__((ext_vector_type(4))) unsigned short;

__device__ __forceinline__ short f2bf(float f) {
    union { float f; unsigned int u; } v; v.f = f;
    unsigned int u = v.u;
    u += 0x7fffu + ((u >> 16) & 1u);
    return (short)(u >> 16);
}
__device__ __forceinline__ float bf2f(unsigned short u) {
    union { unsigned int u; float f; } v; v.u = ((unsigned int)u) << 16; return v.f;
}

// row-swizzle for 16B LDS slots (consistent across all tiles/kernels)
__device__ __forceinline__ int swz(int row) { return (row >> 1) & 7; }

// ---------------- Kernel 1: y_k[bt] = x[bt] @ Theta_k, stored TRANSPOSED ----------------
// yT[k][(bt*64 + o)*512 + u]  (bf16)
__global__ __launch_bounds__(256, 4)
void y_kernel(const float* __restrict__ x, const float* __restrict__ Theta,
              unsigned short* __restrict__ yT)
{
    __shared__ __align__(16) unsigned char smem[32768];
    short* xT = (short*)(smem);

    const int tid = threadIdx.x, lane = tid & 63, q = tid >> 6;
    const int g = lane >> 4, nbase = lane & 15;
    const int bt = blockIdx.x >> 3;
    const int u0 = (blockIdx.x & 7) * 64;

    // stage x tile [row=u][k-slot=f], bf16 swizzled
    {
        const float* xp = x + ((size_t)(bt * VV + u0 + lane)) * FF + q * 16;
        float4 a0 = ((const float4*)xp)[0];
        float4 a1 = ((const float4*)xp)[1];
        float4 a2 = ((const float4*)xp)[2];
        float4 a3 = ((const float4*)xp)[3];
        float v[16] = {a0.x,a0.y,a0.z,a0.w, a1.x,a1.y,a1.z,a1.w,
                       a2.x,a2.y,a2.z,a2.w, a3.x,a3.y,a3.z,a3.w};
        s16x8 p0, p1;
        #pragma unroll
        for (int e = 0; e < 8; ++e) { p0[e] = f2bf(v[e]); p1[e] = f2bf(v[8 + e]); }
        const int fs = swz(lane);
        *(s16x8*)&xT[lane * 64 + (((q * 2)     ^ fs) * 8)] = p0;
        *(s16x8*)&xT[lane * 64 + (((q * 2 + 1) ^ fs) * 8)] = p1;
    }
    // stage ThetaT tiles [row=o][k-slot=f]
    #pragma unroll
    for (int k = 0; k < 3; ++k) {
        short* tk = (short*)(smem + 8192 + k * 8192);
        s16x8 p0, p1;
        #pragma unroll
        for (int e = 0; e < 8; ++e) {
            p0[e] = f2bf(Theta[k * FF * OO + (q * 16 + e) * OO + lane]);
            p1[e] = f2bf(Theta[k * FF * OO + (q * 16 + 8 + e) * OO + lane]);
        }
        const int fs = swz(lane);
        *(s16x8*)&tk[lane * 64 + (((q * 2)     ^ fs) * 8)] = p0;
        *(s16x8*)&tk[lane * 64 + (((q * 2 + 1) ^ fs) * 8)] = p1;
    }
    __syncthreads();

    f32x4 zero = {0.f, 0.f, 0.f, 0.f};
    f32x4 acc[3][4];
    #pragma unroll
    for (int k = 0; k < 3; ++k)
        #pragma unroll
        for (int nt = 0; nt < 4; ++nt) acc[k][nt] = zero;

    const int mrow = q * 16 + nbase;
    const int moff = mrow * 64, ms = swz(mrow);
    #pragma unroll
    for (int kk = 0; kk < 2; ++kk) {
        const int slotA = kk * 4 + g;
        s16x8 a = *(const s16x8*)&xT[moff + ((slotA ^ ms) * 8)];
        #pragma unroll
        for (int nt = 0; nt < 4; ++nt) {
            const int nrow = nt * 16 + nbase;
            const int nad = nrow * 64 + ((slotA ^ swz(nrow)) * 8);
            #pragma unroll
            for (int k = 0; k < 3; ++k) {
                s16x8 b = *(const s16x8*)&((short*)(smem + 8192 + k * 8192))[nad];
                acc[k][nt] = __builtin_amdgcn_mfma_f32_16x16x32_bf16(a, b, acc[k][nt], 0, 0, 0);
            }
        }
    }
    // store transposed: yT[k][(bt*64 + o)*512 + u], r=0..3 are consecutive u
    #pragma unroll
    for (int k = 0; k < 3; ++k) {
        #pragma unroll
        for (int nt = 0; nt < 4; ++nt) {
            const int o = nt * 16 + nbase;
            const int u = u0 + q * 16 + g * 4;
            u16x4 pk;
            #pragma unroll
            for (int r = 0; r < 4; ++r) pk[r] = (unsigned short)f2bf(acc[k][nt][r]);
            *(u16x4*)&yT[(size_t)k * YELEMS + ((size_t)(bt * 64 + o)) * VV + u] = pk;
        }
    }
}

// ---------------- Kernel 2: main fused Chebyshev conv ----------------
__global__ __launch_bounds__(256, 4)
void cheb_main(const float* __restrict__ S, const float* __restrict__ Att,
               const unsigned short* __restrict__ yT, float* __restrict__ out)
{
    __shared__ __align__(16) unsigned char smem[35584];
    short* cT1 = (short*)(smem);
    short* cT2 = (short*)(smem + 8192);
    short* yL1 = (short*)(smem + 16384);
    short* yL2 = (short*)(smem + 24576);
    float* degpart = (float*)(smem + 32768);  // 8*64 f32
    float* degv    = (float*)(smem + 34816);
    float* Adg     = (float*)(smem + 35072);
    float* Sdg     = (float*)(smem + 35328);

    const int tid = threadIdx.x, lane = tid & 63, q = tid >> 6;
    const int nbase = lane & 15, g = lane >> 4;

    // XCD-friendly decode: 8 v-tiles of one bt share wg%8 (same XCD, S stays in L2)
    const int wg = blockIdx.x;
    const int bt = (wg & 7) + ((wg >> 6) << 3);
    const int vt = (wg >> 3) & 7;
    const int v0 = vt * 64;
    const int b  = bt >> 4;

    const float* Sbt = S + (size_t)bt * VV * VV;
    const float* Abt = Att + (size_t)b * VV * VV;
    const unsigned short* y0g = yT + (size_t)bt * 64 * VV;
    const unsigned short* y1g = y0g + (size_t)YELEMS;
    const unsigned short* y2g = y0g + (size_t)2 * YELEMS;

    // coefficient staging map: thread -> v pair (vb, vb+1), u-octet sIdx
    const int vb   = (lane & 31) * 2;
    const int sIdx = q + ((lane >> 5) << 2);
    // y staging map: thread -> o-row, u-slot
    const int yrow  = q * 8 + (lane >> 3);
    const int yslot = lane & 7;

    f32x4 zero = {0.f, 0.f, 0.f, 0.f};
    f32x4 acc1[4], acc2[4];
    #pragma unroll
    for (int i = 0; i < 4; ++i) { acc1[i] = zero; acc2[i] = zero; }
    float dega = 0.f, degb = 0.f;

    const int mrow = q * 16 + nbase;
    const int moff = mrow * 64, ms = swz(mrow);

    for (int ut = 0; ut < 8; ++ut) {
        const int u0t = ut * 64;
        const int ub  = u0t + sIdx * 8;
        // S rows for Smin transpose term (per-thread contiguous 32B x 2 rows)
        const float* sra = Sbt + (size_t)(v0 + vb) * VV + ub;
        float4 ra0 = ((const float4*)sra)[0], ra1 = ((const float4*)sra)[1];
        const float* srb = sra + VV;
        float4 rb0 = ((const float4*)srb)[0], rb1 = ((const float4*)srb)[1];
        float rowa[8] = {ra0.x,ra0.y,ra0.z,ra0.w, ra1.x,ra1.y,ra1.z,ra1.w};
        float rowb[8] = {rb0.x,rb0.y,rb0.z,rb0.w, rb1.x,rb1.y,rb1.z,rb1.w};

        s16x8 p1a, p1b, p2a, p2b;
        #pragma unroll
        for (int e = 0; e < 8; ++e) {
            const int ug = ub + e;
            float2 sc = *(const float2*)&Sbt[(size_t)ug * VV + v0 + vb];
            float2 av = *(const float2*)&Abt[(size_t)ug * VV + v0 + vb];
            float sma = fminf(sc.x, rowa[e]);
            float smb = fminf(sc.y, rowb[e]);
            dega += sma; degb += smb;
            float c1a = -av.x * sma, c1b = -av.y * smb;
            float c2a = 2.0f * av.x * sma * sma, c2b = 2.0f * av.y * smb * smb;
            if (ug == v0 + vb)     { c1a = 0.f; c2a = 0.f; Adg[vb]     = av.x; Sdg[vb]     = sma; }
            if (ug == v0 + vb + 1) { c1b = 0.f; c2b = 0.f; Adg[vb + 1] = av.y; Sdg[vb + 1] = smb; }
            p1a[e] = f2bf(c1a); p1b[e] = f2bf(c1b);
            p2a[e] = f2bf(c2a); p2b[e] = f2bf(c2b);
        }
        const int sa = ((sIdx ^ swz(vb))     * 8);
        const int sb = ((sIdx ^ swz(vb + 1)) * 8);
        *(s16x8*)&cT1[vb * 64 + sa] = p1a;  *(s16x8*)&cT1[(vb + 1) * 64 + sb] = p1b;
        *(s16x8*)&cT2[vb * 64 + sa] = p2a;  *(s16x8*)&cT2[(vb + 1) * 64 + sb] = p2b;

        // stage y tiles: vectorized short8 (contiguous in u thanks to transposed yT)
        #pragma unroll
        for (int p = 0; p < 2; ++p) {
            const int orow = yrow + p * 32;
            const size_t gidx = (size_t)orow * VV + u0t + yslot * 8;
            s16x8 w1 = *(const s16x8*)&y1g[gidx];
            s16x8 w2 = *(const s16x8*)&y2g[gidx];
            const int ad = orow * 64 + ((yslot ^ swz(orow)) * 8);
            *(s16x8*)&yL1[ad] = w1;
            *(s16x8*)&yL2[ad] = w2;
        }
        __syncthreads();

        #pragma unroll
        for (int kk = 0; kk < 2; ++kk) {
            const int slotA = kk * 4 + g;
            s16x8 a1 = *(const s16x8*)&cT1[moff + ((slotA ^ ms) * 8)];
            s16x8 a2 = *(const s16x8*)&cT2[moff + ((slotA ^ ms) * 8)];
            #pragma unroll
            for (int nt = 0; nt < 4; ++nt) {
                const int nrow = nt * 16 + nbase;
                const int nad = nrow * 64 + ((slotA ^ swz(nrow)) * 8);
                s16x8 b1 = *(const s16x8*)&yL1[nad];
                s16x8 b2 = *(const s16x8*)&yL2[nad];
                acc1[nt] = __builtin_amdgcn_mfma_f32_16x16x32_bf16(a1, b1, acc1[nt], 0, 0, 0);
                acc2[nt] = __builtin_amdgcn_mfma_f32_16x16x32_bf16(a2, b2, acc2[nt], 0, 0, 0);
            }
        }
        __syncthreads();
    }

    degpart[sIdx * 64 + vb]     = dega;
    degpart[sIdx * 64 + vb + 1] = degb;
    __syncthreads();
    if (tid < 64) {
        float d = 0.f;
        #pragma unroll
        for (int s = 0; s < 8; ++s) d += degpart[s * 64 + tid];
        degv[tid] = d;
    }
    __syncthreads();

    float* obt = out + (size_t)bt * VV * OO;
    #pragma unroll
    for (int r = 0; r < 4; ++r) {
        const int vloc = q * 16 + g * 4 + r;
        const float Ad = Adg[vloc];
        const float Ld = degv[vloc] - Sdg[vloc] - 1.0f;
        const float w1 = Ad * Ld;
        const float w2 = Ad * (2.0f * Ld * Ld - 1.0f);
        const int vg = v0 + vloc;
        #pragma unroll
        for (int nt = 0; nt < 4; ++nt) {
            const int oo = nt * 16 + nbase;
            const size_t yi = (size_t)oo * VV + vg;
            float y0v = bf2f(y0g[yi]);
            float y1v = bf2f(y1g[yi]);
            float y2v = bf2f(y2g[yi]);
            float val = acc1[nt][r] + acc2[nt][r] + Ad * y0v + w1 * y1v + w2 * y2v;
            obt[(size_t)vg * OO + oo] = fmaxf(val, 0.0f);
        }
    }
}

extern "C" void kernel_launch(void* const* d_in, const int* in_sizes, int n_in,
                              void* d_out, int out_size, void* d_ws, size_t ws_size,
                              hipStream_t stream) {
    (void)in_sizes; (void)n_in; (void)ws_size; (void)out_size;
    const float* x   = (const float*)d_in[0];
    const float* Att = (const float*)d_in[1];
    const float* S   = (const float*)d_in[2];
    const float* Th  = (const float*)d_in[3];
    float* outp = (float*)d_out;
    unsigned short* yT = (unsigned short*)d_ws;  // needs 50,331,648 B
    hipLaunchKernelGGL(y_kernel, dim3(2048), dim3(256), 0, stream, x, Th, yT);
    hipLaunchKernelGGL(cheb_main, dim3(2048), dim3(256), 0, stream, S, Att, yT, outp);
}

// Round 3
// 231.972 us; speedup vs baseline: 1.4143x; 1.0130x over previous
//
#include <hip/hip_runtime.h>

#define VV 512
#define FF 64
#define OO 64
#define Y0E 8388608   // shorts in y0 region (256*64*512)
#define IMGE 8388608  // shorts per image region

using f32x4 = __attribute__((ext_vector_type(4))) float;
using s16x8 = __attribute__((ext_vector_type(8))) short;
using s16x4 = __attribute__((ext_vector_type(4))) short;
using u16x4 = __attribute__((ext_vector_type(4))) unsigned short;

__device__ __forceinline__ short f2bf(float f) {
    union { float f; unsigned int u; } v; v.f = f;
    unsigned int u = v.u;
    u += 0x7fffu + ((u >> 16) & 1u);
    return (short)(u >> 16);
}
__device__ __forceinline__ float bf2f(unsigned short u) {
    union { unsigned int u; float f; } v; v.u = ((unsigned int)u) << 16; return v.f;
}
__device__ __forceinline__ int swz(int row) { return (row >> 1) & 7; }

__device__ __forceinline__ void gload16(const void* g, void* l) {
    __builtin_amdgcn_global_load_lds(
        (const __attribute__((address_space(1))) unsigned int*)g,
        (__attribute__((address_space(3))) unsigned int*)l, 16, 0, 0);
}

// ---------------- Kernel 1: y_k[bt] = x[bt] @ Theta_k ----------------
// y0 plain [bt][o][u]; y1/y2 as pre-swizzled 8kB tile images per (bt, utile)
__global__ __launch_bounds__(256, 4)
void y_kernel(const float* __restrict__ x, const float* __restrict__ Theta,
              unsigned short* __restrict__ yT)
{
    __shared__ __align__(16) unsigned char smem[32768];
    short* xT = (short*)(smem);

    const int tid = threadIdx.x, lane = tid & 63, q = tid >> 6;
    const int g = lane >> 4, nbase = lane & 15;
    const int bt = blockIdx.x >> 3;
    const int utile = blockIdx.x & 7;
    const int u0 = utile * 64;

    {
        const float* xp = x + ((size_t)(bt * VV + u0 + lane)) * FF + q * 16;
        float4 a0 = ((const float4*)xp)[0];
        float4 a1 = ((const float4*)xp)[1];
        float4 a2 = ((const float4*)xp)[2];
        float4 a3 = ((const float4*)xp)[3];
        float v[16] = {a0.x,a0.y,a0.z,a0.w, a1.x,a1.y,a1.z,a1.w,
                       a2.x,a2.y,a2.z,a2.w, a3.x,a3.y,a3.z,a3.w};
        s16x8 p0, p1;
        #pragma unroll
        for (int e = 0; e < 8; ++e) { p0[e] = f2bf(v[e]); p1[e] = f2bf(v[8 + e]); }
        const int fs = swz(lane);
        *(s16x8*)&xT[lane * 64 + (((q * 2)     ^ fs) * 8)] = p0;
        *(s16x8*)&xT[lane * 64 + (((q * 2 + 1) ^ fs) * 8)] = p1;
    }
    #pragma unroll
    for (int k = 0; k < 3; ++k) {
        short* tk = (short*)(smem + 8192 + k * 8192);
        s16x8 p0, p1;
        #pragma unroll
        for (int e = 0; e < 8; ++e) {
            p0[e] = f2bf(Theta[k * FF * OO + (q * 16 + e) * OO + lane]);
            p1[e] = f2bf(Theta[k * FF * OO + (q * 16 + 8 + e) * OO + lane]);
        }
        const int fs = swz(lane);
        *(s16x8*)&tk[lane * 64 + (((q * 2)     ^ fs) * 8)] = p0;
        *(s16x8*)&tk[lane * 64 + (((q * 2 + 1) ^ fs) * 8)] = p1;
    }
    __syncthreads();

    f32x4 zero = {0.f, 0.f, 0.f, 0.f};
    f32x4 acc[3][4];
    #pragma unroll
    for (int k = 0; k < 3; ++k)
        #pragma unroll
        for (int nt = 0; nt < 4; ++nt) acc[k][nt] = zero;

    const int mrow = q * 16 + nbase;
    const int moff = mrow * 64, ms = swz(mrow);
    #pragma unroll
    for (int kk = 0; kk < 2; ++kk) {
        const int slotA = kk * 4 + g;
        s16x8 a = *(const s16x8*)&xT[moff + ((slotA ^ ms) * 8)];
        #pragma unroll
        for (int nt = 0; nt < 4; ++nt) {
            const int nrow = nt * 16 + nbase;
            const int nad = nrow * 64 + ((slotA ^ swz(nrow)) * 8);
            #pragma unroll
            for (int k = 0; k < 3; ++k) {
                s16x8 b = *(const s16x8*)&((short*)(smem + 8192 + k * 8192))[nad];
                acc[k][nt] = __builtin_amdgcn_mfma_f32_16x16x32_bf16(a, b, acc[k][nt], 0, 0, 0);
            }
        }
    }
    // y0 plain
    #pragma unroll
    for (int nt = 0; nt < 4; ++nt) {
        const int o = nt * 16 + nbase;
        u16x4 p0;
        #pragma unroll
        for (int r = 0; r < 4; ++r) p0[r] = (unsigned short)f2bf(acc[0][nt][r]);
        *(u16x4*)&yT[(size_t)bt * 32768 + (size_t)o * VV + u0 + q * 16 + g * 4] = p0;
    }
    // y1/y2 tile images (pre-swizzled: row o, slot = (u_local>>3)^swz(o))
    unsigned short* im1 = yT + (size_t)Y0E + ((size_t)bt * 8 + utile) * 4096;
    unsigned short* im2 = im1 + (size_t)IMGE;
    const int sb = q * 2 + (g >> 1), hf = g & 1;
    #pragma unroll
    for (int nt = 0; nt < 4; ++nt) {
        const int o = nt * 16 + nbase;
        const int ad = o * 64 + ((sb ^ swz(o)) * 8) + hf * 4;
        u16x4 p1, p2;
        #pragma unroll
        for (int r = 0; r < 4; ++r) {
            p1[r] = (unsigned short)f2bf(acc[1][nt][r]);
            p2[r] = (unsigned short)f2bf(acc[2][nt][r]);
        }
        *(u16x4*)&im1[ad] = p1;
        *(u16x4*)&im2[ad] = p2;
    }
}

// ---------------- Kernel 2: main fused Chebyshev conv ----------------
__global__ __launch_bounds__(256, 3)
void cheb_main(const float* __restrict__ S, const float* __restrict__ Att,
               const unsigned short* __restrict__ yT, float* __restrict__ out)
{
    __shared__ __align__(16) unsigned char smem[37632];
    short* cT1 = (short*)(smem);
    short* cT2 = (short*)(smem + 8192);
    short* yL1 = (short*)(smem + 16384);
    short* yL2 = (short*)(smem + 24576);
    float* degpart = (float*)(smem + 32768);   // 16*64 f32
    float* degv    = (float*)(smem + 36864);
    float* Adg     = (float*)(smem + 37120);
    float* Sdg     = (float*)(smem + 37376);

    const int tid = threadIdx.x, lane = tid & 63, q = tid >> 6;
    const int nbase = lane & 15, g = lane >> 4;

    const int wg = blockIdx.x;
    const int bt = (wg & 7) + ((wg >> 6) << 3);
    const int vt = (wg >> 3) & 7;
    const int v0 = vt * 64;
    const int b  = bt >> 4;

    const float* Sbt = S + (size_t)bt * VV * VV;
    const float* Abt = Att + (size_t)b * VV * VV;
    const unsigned short* y0p  = yT + (size_t)bt * 64 * VV;
    const unsigned short* img1 = yT + (size_t)Y0E + (size_t)bt * 8 * 4096;
    const unsigned short* img2 = img1 + (size_t)IMGE;

    const int vq   = (lane & 15) * 4;          // v-quad base (tile-local)
    const int tIdx = (lane >> 4) + q * 4;      // u-quad index 0..15

    f32x4 zero = {0.f,0.f,0.f,0.f};
    f32x4 acc1[4], acc2[4];
    #pragma unroll
    for (int i = 0; i < 4; ++i) { acc1[i] = zero; acc2[i] = zero; }
    float da[4] = {0.f, 0.f, 0.f, 0.f};

    const int mrow = q * 16 + nbase;
    const int moff = mrow * 64, ms = swz(mrow);

    // prologue: load ut=0 S-col / A-col / S-row quads (all float4)
    f32x4 csc[4], cac[4], csr[4];
    {
        const float* sb = Sbt + (size_t)(tIdx * 4) * VV + v0 + vq;
        const float* ab = Abt + (size_t)(tIdx * 4) * VV + v0 + vq;
        const float* rb = Sbt + (size_t)(v0 + vq) * VV + tIdx * 4;
        #pragma unroll
        for (int e = 0; e < 4; ++e) {
            csc[e] = *(const f32x4*)(sb + e * VV);
            cac[e] = *(const f32x4*)(ab + e * VV);
            csr[e] = *(const f32x4*)(rb + e * VV);
        }
    }

    #pragma unroll
    for (int ut = 0; ut < 8; ++ut) {
        // DMA this iteration's y tiles into LDS (pre-swizzled images, linear dest)
        {
            const char* t1 = (const char*)img1 + (size_t)ut * 8192;
            const char* t2 = (const char*)img2 + (size_t)ut * 8192;
            const int wo = q * 1024 + lane * 16;
            gload16(t1 + wo,        (char*)yL1 + q * 1024);
            gload16(t1 + wo + 4096, (char*)yL1 + q * 1024 + 4096);
            gload16(t2 + wo,        (char*)yL2 + q * 1024);
            gload16(t2 + wo + 4096, (char*)yL2 + q * 1024 + 4096);
        }
        // prefetch next iteration's S/A data into registers
        f32x4 nsc[4], nac[4], nsr[4];
        if (ut < 7) {
            const int u0n = (ut + 1) * 64;
            const float* sb = Sbt + (size_t)(u0n + tIdx * 4) * VV + v0 + vq;
            const float* ab = Abt + (size_t)(u0n + tIdx * 4) * VV + v0 + vq;
            const float* rb = Sbt + (size_t)(v0 + vq) * VV + u0n + tIdx * 4;
            #pragma unroll
            for (int e = 0; e < 4; ++e) {
                nsc[e] = *(const f32x4*)(sb + e * VV);
                nac[e] = *(const f32x4*)(ab + e * VV);
                nsr[e] = *(const f32x4*)(rb + e * VV);
            }
        }
        // coefficient VALU + LDS write (consumes current regs)
        const bool dtile = (ut == vt);
        #pragma unroll
        for (int j = 0; j < 4; ++j) {
            s16x4 p1, p2;
            #pragma unroll
            for (int e = 0; e < 4; ++e) {
                float sm = fminf(csc[e][j], csr[j][e]);
                da[j] += sm;
                float a = cac[e][j];
                float c1 = -a * sm;
                float c2 = (a + a) * (sm * sm);
                if (dtile && (tIdx * 4 + e == vq + j)) {
                    c1 = 0.f; c2 = 0.f;
                    Adg[vq + j] = a; Sdg[vq + j] = sm;
                }
                p1[e] = f2bf(c1);
                p2[e] = f2bf(c2);
            }
            const int ad = (vq + j) * 64 + (((tIdx >> 1) ^ swz(vq + j)) * 8) + (tIdx & 1) * 4;
            *(s16x4*)&cT1[ad] = p1;
            *(s16x4*)&cT2[ad] = p2;
        }
        __syncthreads();
        #pragma unroll
        for (int kk = 0; kk < 2; ++kk) {
            const int slotA = kk * 4 + g;
            s16x8 a1 = *(const s16x8*)&cT1[moff + ((slotA ^ ms) * 8)];
            s16x8 a2 = *(const s16x8*)&cT2[moff + ((slotA ^ ms) * 8)];
            #pragma unroll
            for (int nt = 0; nt < 4; ++nt) {
                const int nrow = nt * 16 + nbase;
                const int nad = nrow * 64 + ((slotA ^ swz(nrow)) * 8);
                s16x8 b1 = *(const s16x8*)&yL1[nad];
                s16x8 b2 = *(const s16x8*)&yL2[nad];
                acc1[nt] = __builtin_amdgcn_mfma_f32_16x16x32_bf16(a1, b1, acc1[nt], 0, 0, 0);
                acc2[nt] = __builtin_amdgcn_mfma_f32_16x16x32_bf16(a2, b2, acc2[nt], 0, 0, 0);
            }
        }
        __syncthreads();
        if (ut < 7) {
            #pragma unroll
            for (int e = 0; e < 4; ++e) { csc[e] = nsc[e]; cac[e] = nac[e]; csr[e] = nsr[e]; }
        }
    }

    // deg reduction
    #pragma unroll
    for (int j = 0; j < 4; ++j) degpart[tIdx * 64 + vq + j] = da[j];
    __syncthreads();
    if (tid < 64) {
        float d = 0.f;
        #pragma unroll
        for (int s = 0; s < 16; ++s) d += degpart[s * 64 + tid];
        degv[tid] = d;
    }
    __syncthreads();

    // epilogue: combine off-diag MFMA result with exact diagonal path
    float* obt = out + (size_t)bt * VV * OO;
    const unsigned short* t1v = img1 + (size_t)vt * 4096;
    const unsigned short* t2v = img2 + (size_t)vt * 4096;
    #pragma unroll
    for (int r = 0; r < 4; ++r) {
        const int vloc = q * 16 + g * 4 + r;
        const int vg = v0 + vloc;
        const float Ad = Adg[vloc];
        const float Ld = degv[vloc] - Sdg[vloc] - 1.0f;
        const float w1 = Ad * Ld;
        const float w2 = Ad * (2.0f * Ld * Ld - 1.0f);
        #pragma unroll
        for (int nt = 0; nt < 4; ++nt) {
            const int oo = nt * 16 + nbase;
            const int idx = oo * 64 + (((vloc >> 3) ^ swz(oo)) * 8) + (vloc & 7);
            float y0v = bf2f(y0p[(size_t)oo * VV + vg]);
            float y1v = bf2f(t1v[idx]);
            float y2v = bf2f(t2v[idx]);
            float val = acc1[nt][r] + acc2[nt][r] + Ad * y0v + w1 * y1v + w2 * y2v;
            obt[(size_t)vg * OO + oo] = fmaxf(val, 0.0f);
        }
    }
}

extern "C" void kernel_launch(void* const* d_in, const int* in_sizes, int n_in,
                              void* d_out, int out_size, void* d_ws, size_t ws_size,
                              hipStream_t stream) {
    (void)in_sizes; (void)n_in; (void)ws_size; (void)out_size;
    const float* x   = (const float*)d_in[0];
    const float* Att = (const float*)d_in[1];
    const float* S   = (const float*)d_in[2];
    const float* Th  = (const float*)d_in[3];
    float* outp = (float*)d_out;
    unsigned short* yT = (unsigned short*)d_ws;  // needs 50,331,648 B
    hipLaunchKernelGGL(y_kernel, dim3(2048), dim3(256), 0, stream, x, Th, yT);
    hipLaunchKernelGGL(cheb_main, dim3(2048), dim3(256), 0, stream, S, Att, yT, outp);
}